// Round 3
// baseline (315.044 us; speedup 1.0000x reference)
//
#include <hip/hip_runtime.h>

#define DIM 1024
#define HEADS 16
#define DHEAD 64
#define SEQ 2048
#define BATCH 4
#define ROWS (BATCH*SEQ)        // 8192
#define QK_COLS (3*DIM)         // 3072
// SCALE * log2(e) folded into Q so softmax runs in base-2 space (identical result)
#define QSCALE 0.18033688011112042f

typedef __bf16 bf16x8 __attribute__((ext_vector_type(8)));
typedef __bf16 bf16x4 __attribute__((ext_vector_type(4)));
typedef short s16x4 __attribute__((ext_vector_type(4)));
typedef float f32x4 __attribute__((ext_vector_type(4)));
typedef unsigned short u16;
typedef unsigned int u32;

__device__ __forceinline__ u16 f2bf(float f) {
  u32 u = __float_as_uint(f);
  u = (u + 0x7fffu + ((u >> 16) & 1u)) >> 16;
  return (u16)u;
}

__device__ __forceinline__ void gld16(const void* g, void* s) {
  __builtin_amdgcn_global_load_lds((__attribute__((address_space(1))) void*)g,
                                   (__attribute__((address_space(3))) void*)s, 16, 0, 0);
}

// raw v_exp_f32; device-only builtin hidden from host pass
__device__ __forceinline__ float fexp2(float x) {
#if defined(__HIP_DEVICE_COMPILE__)
  return __builtin_amdgcn_exp2f(x);
#else
  return x;
#endif
}

__device__ __forceinline__ s16x4 pack_bf16(f32x4 v) {
  bf16x4 b = __builtin_convertvector(v, bf16x4);
  union { bf16x4 b; s16x4 s; } u; u.b = b; return u.s;
}

// ------------- fused prep: LayerNorm + both weight transposes (one launch) -------------
__global__ __launch_bounds__(256) void prep_kernel(
    const float* __restrict__ x, const float* __restrict__ gam, const float* __restrict__ bet,
    u16* __restrict__ xn,
    const float* __restrict__ wqkv, u16* __restrict__ wqkvT,
    const float* __restrict__ wout, u16* __restrict__ woutT) {
  __shared__ float tile[32][33];
  int bid = blockIdx.x, tid = threadIdx.x;
  if (bid < ROWS) {
    int lane = tid & 63, w = tid >> 6;
    const float4 xv = *(const float4*)(x + (size_t)bid*DIM + tid*4);
    float s = xv.x + xv.y + xv.z + xv.w;
    float q = xv.x*xv.x + xv.y*xv.y + xv.z*xv.z + xv.w*xv.w;
    for (int off = 32; off > 0; off >>= 1) { s += __shfl_xor(s, off, 64); q += __shfl_xor(q, off, 64); }
    float* red = &tile[0][0];
    if (lane == 0) { red[w] = s; red[4+w] = q; }
    __syncthreads();
    s = red[0]+red[1]+red[2]+red[3];
    q = red[4]+red[5]+red[6]+red[7];
    float mean = s * (1.0f/DIM);
    float rstd = rsqrtf(q*(1.0f/DIM) - mean*mean + 1e-5f);
    float4 gv = *(const float4*)(gam + tid*4);
    float4 bv = *(const float4*)(bet + tid*4);
    ushort4 o;
    o.x = f2bf((xv.x-mean)*rstd*gv.x + bv.x);
    o.y = f2bf((xv.y-mean)*rstd*gv.y + bv.y);
    o.z = f2bf((xv.z-mean)*rstd*gv.z + bv.z);
    o.w = f2bf((xv.w-mean)*rstd*gv.w + bv.w);
    *(ushort4*)(xn + (size_t)bid*DIM + tid*4) = o;
  } else {
    const float* in; u16* out; int R, C, c0, r0;
    if (bid < ROWS + 3072) {
      int t = bid - ROWS;
      in = wqkv; out = wqkvT; R = DIM; C = QK_COLS;
      c0 = (t % 96) * 32; r0 = (t / 96) * 32;
    } else {
      int t = bid - ROWS - 3072;
      in = wout; out = woutT; R = DIM; C = DIM;
      c0 = (t & 31) * 32; r0 = (t >> 5) * 32;
    }
    int tx = tid & 31, ty = tid >> 5;
    for (int i = 0; i < 32; i += 8)
      tile[ty+i][tx] = in[(size_t)(r0+ty+i)*C + c0 + tx];
    __syncthreads();
    for (int i = 0; i < 32; i += 8)
      out[(size_t)(c0+ty+i)*R + r0 + tx] = f2bf(tile[tx][ty+i]);
  }
}

// ---------------- GEMM v2: 256x256 tile, BK=64, 8-phase counted-vmcnt schedule ----------
// T3+T4+T5 port (learn_hip m201 template, ledger re-derived for this K=1024 shape):
//  - 8 waves (2M x 4N), per-wave 128x64 output, acc[32] f32x4.
//  - LDS 128 KiB: 2 dbuf x {A[256][32]ks0, A[..]ks1, B[256][32]ks0, B[..]ks1} (K-half
//    regions, 64B row pitch -> ds_read_b128 conflict-free: 8 lanes/bank-group = min).
//  - Phase = (dbuf, mi-half, ks): 8 ds_read_b128 + 1 half-region stage (2 gld16) +
//    raw s_barrier + 16 MFMA (setprio-wrapped) + raw s_barrier. NO vmcnt(0) drain.
//  - Stage rotation: each phase stages the region last READ one phase earlier:
//    P1:A1(1)<-t(2k+1)kh1 P2:B1(1) P3:A0(0)<-t(2k+2) P4:B0(0) P5:A1(0) P6:B1(0)
//    P7:A0(1)<-t(2k+3) P8:B0(1). Counted s_waitcnt vmcnt(4) ONLY at P4/P8 (confirms
//    all loads a 6-phase-later reader needs); vmcnt(0) only on the last iteration.
//  - Bijective XCD swizzle on flat blockIdx (nwg % 8 == 0 for both call sites).
// EPI 0 epilogues (Q scale / K col-swizzle / V pi-permute+swizzle) and EPI 1 (fp32)
// keep the round-2 index math, re-parameterized to the 2x4 wave grid.
template<int EPI>
__global__ __launch_bounds__(512, 2) void gemm256(const u16* __restrict__ A, const u16* __restrict__ Bt,
                                                  void* __restrict__ Cv, u16* __restrict__ vT,
                                                  int K, int NBN, int NOUT) {
  __shared__ alignas(16) u16 smem[65536];  // 128 KiB
  int tid = threadIdx.x;
  int lane = tid & 63, w = tid >> 6;       // w in 0..7
  int l = lane & 15, quad = lane >> 4;
  int wr = w >> 2, wc = w & 3;             // wave grid 2(M) x 4(N)
  int nwg = gridDim.x;
  int qq8 = nwg >> 3;                      // nwg % 8 == 0 at both call sites
  int wg = (blockIdx.x & 7) * qq8 + (blockIdx.x >> 3);
  int bm = wg / NBN, bn = wg % NBN;
  int m0 = bm * 256, n0 = bn * 256;
  const u16* Ag = A + (size_t)m0 * K;
  const u16* Bg = Bt + (size_t)n0 * K;
  bool sw = (EPI == 1) || (n0 < 2048);     // swapped orientation for Q,K,out-proj
  f32x4 z = {0.f, 0.f, 0.f, 0.f};
  f32x4 acc[32];
  #pragma unroll
  for (int i = 0; i < 32; ++i) acc[i] = z;

  // region offsets (u16 units): dbuf d at d*32768; A ks-half at ks*8192; B at +16384
  #define AOFF(d, ks) ((d)*32768 + (ks)*8192)
  #define BOFF(d, ks) ((d)*32768 + 16384 + (ks)*8192)
  // stage one 16KB region ([256 rows][32 cols]): 2 x gld16 per thread, linear LDS dest
  #define STG(dstOff, srcG, kofs) do { \
    _Pragma("unroll") \
    for (int c_ = 0; c_ < 2; ++c_) { \
      int ch_ = c_*512 + tid; \
      gld16((srcG) + (size_t)(ch_ >> 2)*K + (kofs) + ((ch_ & 3) << 3), \
            smem + (dstOff) + ch_*8); \
    } } while (0)

  #define PHASE(d, h, ks, STAGE, VMN) do { \
    const u16* Ar_ = smem + AOFF(d, ks); \
    const u16* Br_ = smem + BOFF(d, ks); \
    bf16x8 af_[4], bf_[4]; \
    _Pragma("unroll") \
    for (int mi = 0; mi < 4; ++mi) \
      af_[mi] = *(const bf16x8*)(Ar_ + (wr*128 + (h)*64 + mi*16 + l)*32 + quad*8); \
    _Pragma("unroll") \
    for (int ni = 0; ni < 4; ++ni) \
      bf_[ni] = *(const bf16x8*)(Br_ + (wc*64 + ni*16 + l)*32 + quad*8); \
    STAGE; \
    __builtin_amdgcn_s_barrier(); \
    __builtin_amdgcn_s_setprio(1); \
    if (sw) { \
      _Pragma("unroll") \
      for (int ni = 0; ni < 4; ++ni) \
        _Pragma("unroll") \
        for (int mi = 0; mi < 4; ++mi) \
          acc[ni*8 + (h)*4 + mi] = __builtin_amdgcn_mfma_f32_16x16x32_bf16(bf_[ni], af_[mi], acc[ni*8 + (h)*4 + mi], 0, 0, 0); \
    } else { \
      _Pragma("unroll") \
      for (int mi = 0; mi < 4; ++mi) \
        _Pragma("unroll") \
        for (int ni = 0; ni < 4; ++ni) \
          acc[((h)*4 + mi)*4 + ni] = __builtin_amdgcn_mfma_f32_16x16x32_bf16(af_[mi], bf_[ni], acc[((h)*4 + mi)*4 + ni], 0, 0, 0); \
    } \
    __builtin_amdgcn_s_setprio(0); \
    VMN; \
    __builtin_amdgcn_s_barrier(); \
  } while (0)

  // prologue: tile0 complete + tile1 kh0; confirm tile0 landed (12 issued, allow 4)
  STG(AOFF(0,0), Ag, 0);  STG(BOFF(0,0), Bg, 0);
  STG(AOFF(0,1), Ag, 32); STG(BOFF(0,1), Bg, 32);
  STG(AOFF(1,0), Ag, 64); STG(BOFF(1,0), Bg, 64);
  __asm__ volatile("s_waitcnt vmcnt(4)" ::: "memory");
  __builtin_amdgcn_s_barrier();

  int NT2 = K >> 7;   // iterations of 2 K-tiles (K=1024 -> 8)
  for (int t = 0; t < NT2; ++t) {
    bool nl = (t < NT2 - 1);
    int k1 = (2*t + 1) * 64, k2 = (2*t + 2) * 64, k3 = (2*t + 3) * 64;
    PHASE(0,0,0, { STG(AOFF(1,1), Ag, k1+32); }, {});
    PHASE(0,1,0, { STG(BOFF(1,1), Bg, k1+32); }, {});
    PHASE(0,0,1, { if (nl) STG(AOFF(0,0), Ag, k2); }, {});
    PHASE(0,1,1, { if (nl) STG(BOFF(0,0), Bg, k2); },
          { if (nl) __asm__ volatile("s_waitcnt vmcnt(4)" ::: "memory");
            else    __asm__ volatile("s_waitcnt vmcnt(0)" ::: "memory"); });
    PHASE(1,0,0, { if (nl) STG(AOFF(0,1), Ag, k2+32); }, {});
    PHASE(1,1,0, { if (nl) STG(BOFF(0,1), Bg, k2+32); }, {});
    PHASE(1,0,1, { if (nl) STG(AOFF(1,0), Ag, k3); }, {});
    PHASE(1,1,1, { if (nl) STG(BOFF(1,0), Bg, k3); },
          { if (nl) __asm__ volatile("s_waitcnt vmcnt(4)" ::: "memory");
            else    __asm__ volatile("s_waitcnt vmcnt(0)" ::: "memory"); });
  }

  if (EPI == 0) {
    u16* C = (u16*)Cv;
    int region = n0 >> 10;  // 0=Q, 1=K, 2=V; 256-wide block never straddles
    if (region == 0) {
      #pragma unroll
      for (int ni = 0; ni < 4; ++ni)
        #pragma unroll
        for (int mi = 0; mi < 8; ++mi) {
          int n = n0 + wc*64 + ni*16 + quad*4;       // 4 consecutive cols
          int m = m0 + wr*128 + mi*16 + l;
          f32x4 v = acc[ni*8 + mi] * QSCALE;
          *(s16x4*)(C + (size_t)m*QK_COLS + n) = pack_bf16(v);
        }
    } else if (region == 1) {
      #pragma unroll
      for (int ni = 0; ni < 4; ++ni)
        #pragma unroll
        for (int mi = 0; mi < 8; ++mi) {
          int nq = n0 + wc*64 + ni*16 + quad*4;
          int m  = m0 + wr*128 + mi*16 + l;
          int d  = nq & 63;
          int col = (nq & ~63) | ((((d >> 3) ^ (m & 7)) << 3) | (d & 7));
          *(s16x4*)(C + (size_t)m*QK_COLS + col) = pack_bf16(acc[ni*8 + mi]);
        }
    } else {
      // V: normal orientation; lane holds 4 consecutive seq rows (one pi-group)
      #pragma unroll
      for (int mi = 0; mi < 8; ++mi)
        #pragma unroll
        for (int ni = 0; ni < 4; ++ni) {
          int mrow = m0 + wr*128 + mi*16 + quad*4;   // 4 consecutive seq indices
          int hd   = (n0 - 2048) + wc*64 + ni*16 + l;
          int h = hd >> 6, d = hd & 63;
          int bb = mrow >> 11, nloc = mrow & 2047;
          int jloc = nloc & 31;
          int hi = jloc >> 4;                        // pi: e0 = hi*4
          int u  = ((nloc >> 5) & 3) * 4 + ((jloc >> 2) & 3);  // jb*4 + q
          int c16 = u ^ (d & 15);                    // 16B-chunk bank swizzle
          int p = (nloc & ~127) | (c16 << 3) | (hi << 2);
          *(s16x4*)(vT + ((size_t)(bb*16 + h)*DHEAD + d)*SEQ + p) = pack_bf16(acc[mi*4 + ni]);
        }
    }
  } else {
    float* C = (float*)Cv;
    #pragma unroll
    for (int ni = 0; ni < 4; ++ni)
      #pragma unroll
      for (int mi = 0; mi < 8; ++mi) {
        int n = n0 + wc*64 + ni*16 + quad*4;
        int m = m0 + wr*128 + mi*16 + l;
        *(f32x4*)(C + (size_t)m*NOUT + n) = acc[ni*8 + mi];
      }
  }
  #undef PHASE
  #undef STG
  #undef AOFF
  #undef BOFF
}

// ---------------- Flash attention, S^T formulation, double-buffered, max-free softmax ----
// (unchanged from round 2: K=32 PV via pi-permuted V^T)
__global__ __launch_bounds__(256, 2) void attn_kernel(const u16* __restrict__ qkv,
    const u16* __restrict__ vT, u16* __restrict__ aout) {
  __shared__ alignas(16) u16 smem[32768];  // buf0: Kt[0:8192]|Vt[8192:16384]; buf1: +16384
  int tid = threadIdx.x;
  int lane = tid & 63, w = tid >> 6;       // w in 0..3
  int l = lane & 15, quad = lane >> 4;
  int bh = blockIdx.x, qt = blockIdx.y;
  int b = bh >> 4, h = bh & 15;
  int qrow0 = b*SEQ + qt*128;

  bf16x8 aq[2][2];
  #pragma unroll
  for (int mt = 0; mt < 2; ++mt)
    #pragma unroll
    for (int ks = 0; ks < 2; ++ks)
      aq[mt][ks] = *(const bf16x8*)(qkv + (size_t)(qrow0 + w*32 + mt*16 + l)*QK_COLS + h*DHEAD + ks*32 + quad*8);

  f32x4 z = {0.f,0.f,0.f,0.f};
  f32x4 o[4][2];       // O^T[d=16dt+4q+r][m=16mt+l]
  #pragma unroll
  for (int dt = 0; dt < 4; ++dt) for (int mt = 0; mt < 2; ++mt) o[dt][mt] = z;
  f32x4 psum[2] = {z, z};   // per-lane partial row-sums (reduced once at end)

  const u16* kbase = qkv + (size_t)b*SEQ*QK_COLS + DIM + h*DHEAD;
  const u16* vbase = vT + (size_t)bh*DHEAD*SEQ;

  #pragma unroll
  for (int c = 0; c < 4; ++c) {
    int idx = c*256 + tid;
    gld16(kbase + (size_t)(idx >> 3)*QK_COLS + ((idx & 7) << 3), smem + idx*8);
    gld16(vbase + (size_t)(idx >> 4)*SEQ + ((idx & 15) << 3), smem + 8192 + idx*8);
  }

  for (int kt = 0; kt < 16; ++kt) {
    __syncthreads();  // drains vmcnt: buf[kt&1] staged; prior reads of other buf done
    const u16* Kt = smem + (kt & 1)*16384;
    const u16* Vt = Kt + 8192;
    if (kt < 15) {
      u16* dst = (u16*)smem + ((kt+1) & 1)*16384;
      int krow0 = (kt+1)*128;
      #pragma unroll
      for (int c = 0; c < 4; ++c) {
        int idx = c*256 + tid;
        gld16(kbase + (size_t)(krow0 + (idx >> 3))*QK_COLS + ((idx & 7) << 3), dst + idx*8);
        gld16(vbase + (size_t)(idx >> 4)*SEQ + krow0 + ((idx & 15) << 3), dst + 8192 + idx*8);
      }
    }

    s16x4 pb[2][8];   // P^T bf16 fragments; jt-pairs become K=32 B-frags
    #pragma unroll
    for (int mt = 0; mt < 2; ++mt) {
      f32x4 st[8];
      #pragma unroll
      for (int jt = 0; jt < 8; ++jt) st[jt] = z;
      #pragma unroll
      for (int jt = 0; jt < 8; ++jt) {
        #pragma unroll
        for (int ks = 0; ks < 2; ++ks) {
          bf16x8 bk = *(const bf16x8*)(Kt + (jt*16 + l)*64 + (((ks*4 + quad) ^ (l & 7)) << 3));
          st[jt] = __builtin_amdgcn_mfma_f32_16x16x32_bf16(bk, aq[mt][ks], st[jt], 0,0,0);
        }
      }
      #pragma unroll
      for (int jt = 0; jt < 8; ++jt) {
        f32x4 p;
        p[0] = fexp2(st[jt][0]); p[1] = fexp2(st[jt][1]);
        p[2] = fexp2(st[jt][2]); p[3] = fexp2(st[jt][3]);
        psum[mt] += p;
        pb[mt][jt] = pack_bf16(p);
      }
    }

    // O^T += V^T P^T  (K=32 mfma; av chunks pi-permuted + XOR(d&15)-swizzled in vT)
    #pragma unroll
    for (int jb = 0; jb < 4; ++jb) {
      union { s16x4 h[2]; bf16x8 v; } p0, p1;
      p0.h[0] = pb[0][2*jb]; p0.h[1] = pb[0][2*jb+1];
      p1.h[0] = pb[1][2*jb]; p1.h[1] = pb[1][2*jb+1];
      #pragma unroll
      for (int dt = 0; dt < 4; ++dt) {
        int d = dt*16 + l;
        bf16x8 av = *(const bf16x8*)(Vt + d*128 + (((jb*4 + quad) ^ l) << 3));
        o[dt][0] = __builtin_amdgcn_mfma_f32_16x16x32_bf16(av, p0.v, o[dt][0], 0,0,0);
        o[dt][1] = __builtin_amdgcn_mfma_f32_16x16x32_bf16(av, p1.v, o[dt][1], 0,0,0);
      }
    }
  }

  float li[2];
  #pragma unroll
  for (int mt = 0; mt < 2; ++mt) {
    float ps = psum[mt][0] + psum[mt][1] + psum[mt][2] + psum[mt][3];
    ps += __shfl_xor(ps, 16, 64);
    ps += __shfl_xor(ps, 32, 64);
    li[mt] = ps;
  }

  __syncthreads();  // all waves done reading buffers
  u16* Ep = smem + w*2304;
  #pragma unroll
  for (int mt = 0; mt < 2; ++mt) {
    float inv = 1.0f / li[mt];
    #pragma unroll
    for (int dt = 0; dt < 4; ++dt)
      #pragma unroll
      for (int r = 0; r < 4; ++r)
        Ep[(mt*16 + l)*72 + dt*16 + quad*4 + r] = f2bf(o[dt][mt][r] * inv);
  }
  __asm__ volatile("s_waitcnt lgkmcnt(0)" ::: "memory");
  int lr = lane >> 1, half = lane & 1;
  size_t grow = (size_t)qrow0 + w*32 + lr;
  #pragma unroll
  for (int k = 0; k < 4; ++k) {
    uint4 vv = *(const uint4*)(Ep + lr*72 + half*32 + k*8);
    *(uint4*)(aout + grow*DIM + h*DHEAD + half*32 + k*8) = vv;
  }
}

extern "C" void kernel_launch(void* const* d_in, const int* in_sizes, int n_in,
                              void* d_out, int out_size, void* d_ws, size_t ws_size,
                              hipStream_t stream) {
  const float* x    = (const float*)d_in[0];
  const float* gam  = (const float*)d_in[1];
  const float* bet  = (const float*)d_in[2];
  const float* wqkv = (const float*)d_in[3];
  const float* wout = (const float*)d_in[4];
  float* out = (float*)d_out;

  // workspace layout (bf16 elements), total ~104 MB
  u16* xn    = (u16*)d_ws;                          // 8192*1024
  u16* wqkvT = xn    + (size_t)ROWS*DIM;            // 3072*1024  [N][K]
  u16* woutT = wqkvT + (size_t)QK_COLS*DIM;         // 1024*1024  [N][K]
  u16* qkvb  = woutT + (size_t)DIM*DIM;             // 8192*3072  (Q scaled, K swizzled; V region unused)
  u16* vTb   = qkvb  + (size_t)ROWS*QK_COLS;        // 64*64*2048 V^T per (b,h), pi-permuted+swizzled
  u16* aoutb = vTb   + (size_t)64*DHEAD*SEQ;        // 8192*1024

  prep_kernel<<<ROWS + 3072 + 1024, 256, 0, stream>>>(x, gam, bet, xn, wqkv, wqkvT, wout, woutT);
  gemm256<0><<<(ROWS/256)*(QK_COLS/256), 512, 0, stream>>>(xn, wqkvT, (void*)qkvb, vTb, DIM, QK_COLS/256, 0);
  attn_kernel<<<dim3(64, SEQ/128), 256, 0, stream>>>(qkvb, vTb, aoutb);
  gemm256<1><<<(ROWS/256)*(DIM/256), 512, 0, stream>>>(aoutb, woutT, (void*)out, nullptr, DIM, DIM/256, DIM);
}